// Round 7
// baseline (158.555 us; speedup 1.0000x reference)
//
#include <hip/hip_runtime.h>

#define IN_F   50000
#define OUT_F  50000
#define NNZ_N  800000
#define BATCH  256
#define ELL_CAP 32
#define OVF_CAP 4096
#define NXCD    8
#define ROWS_PER_SLICE (OUT_F / NXCD)     // 6250, exact
#define BUCKET_CAP 112640                 // 110*1024; expected fill ~100K +- 0.3K
#define BUILD_CHUNK 1024                  // entries per build block

static constexpr size_t align256(size_t x) { return (x + 255) & ~size_t(255); }

// ---------------- ws layout (bucketed-ELL path) ----------------
static constexpr size_t OFF_OVFCNT = 0;                                   // int
static constexpr size_t OFF_BCUR   = 64;                                  // 8 ints
static constexpr size_t OFF_ECNT   = 256;                                 // OUT_F ints
static constexpr size_t OFF_OVF    = OFF_ECNT + align256(4 * OUT_F);      // OVF_CAP int2
static constexpr size_t OFF_ELL    = OFF_OVF + align256(8 * OVF_CAP);     // OUT_F*ELL_CAP u32
static constexpr size_t OFF_XB     = OFF_ELL + align256((size_t)4 * OUT_F * ELL_CAP);
static constexpr size_t OFF_BK     = OFF_XB + align256((size_t)2 * IN_F * BATCH);
static constexpr size_t WS_PART    = OFF_BK + align256((size_t)8 * NXCD * BUCKET_CAP);

// ---------------- CSR fallback ws layout (insurance only) ----------------
static constexpr size_t OFF_FLAG = 0;
static constexpr size_t OFF_CNT  = 256;
static constexpr size_t OFF_PTR  = OFF_CNT + align256(4 * (OUT_F + 1));
static constexpr size_t OFF_CUR  = OFF_PTR + align256(4 * (OUT_F + 1));
static constexpr size_t OFF_COL  = OFF_CUR + align256(4 * OUT_F);
static constexpr size_t OFF_VAL  = OFF_COL + align256(4 * NNZ_N);
static constexpr size_t WS_CSR   = OFF_VAL + align256(4 * NNZ_N);

// ---------------------------------------------------------------------------
// int64 vs int32 detection: index values < 50000, so int64 hi-words are 0.
// ---------------------------------------------------------------------------
__device__ __forceinline__ int detect_is32_inline(const void* p) {
    const unsigned* u = (const unsigned*)p;
    int is32 = 0;
    #pragma unroll
    for (int k = 0; k < 8; ++k) is32 |= (u[2 * k + 1] != 0u);
    return is32;
}

__device__ __forceinline__ int load_index(const void* p, int elem, int is32) {
    if (is32) return ((const int*)p)[elem];
    return (int)((const long long*)p)[elem];
}

__device__ __forceinline__ unsigned rtn_bf16(float f) {
    unsigned u = __float_as_uint(f);
    return (u + 0x7FFFu + ((u >> 16) & 1u)) >> 16;
}
__device__ __forceinline__ unsigned pack2_bf16(float a, float b) {
    return rtn_bf16(a) | (rtn_bf16(b) << 16);
}

#define NORM_BLKS (NNZ_N / 256)              // 3125
#define ZERO_BLKS 49                         // ceil(200000/16/256)
#define CONV_BLKS (IN_F * BATCH / 8 / 256)   // 6250
#define BUILD_BLKS (NXCD * (BUCKET_CAP / BUILD_CHUNK))  // 880

// ===========================================================================
// Kernel A: normalize nnz -> (r, cv) pairs binned into 8 row-slice buckets
// (LDS-aggregated cursors: 1 global atomic per slice per block), plus extra
// blocks that zero cnt[]. cv = u16 col | bf16 val << 16.
// ===========================================================================
__global__ void bin_kernel(const void* __restrict__ indices,
                           const float* __restrict__ values,
                           int* __restrict__ bcur,
                           int2* __restrict__ buckets,
                           int* __restrict__ cnt,
                           int* __restrict__ ovf_cnt,
                           int2* __restrict__ ovf) {
    int b = blockIdx.x;
    if (b < NORM_BLKS) {
        __shared__ int lcnt[NXCD];
        __shared__ int lbase[NXCD];
        int tid = threadIdx.x;
        if (tid < NXCD) lcnt[tid] = 0;
        __syncthreads();
        int i = b * 256 + tid;
        int is32 = detect_is32_inline(indices);
        int r = load_index(indices, i, is32);
        int c = load_index(indices, NNZ_N + i, is32);
        unsigned cv = (unsigned)(c & 0xFFFF) | (rtn_bf16(values[i]) << 16);
        int slice = r / ROWS_PER_SLICE;
        int my = atomicAdd(&lcnt[slice], 1);
        __syncthreads();
        if (tid < NXCD) lbase[tid] = atomicAdd(&bcur[tid], lcnt[tid]);
        __syncthreads();
        int pos = lbase[slice] + my;
        int2 e; e.x = r; e.y = (int)cv;
        if (pos < BUCKET_CAP) {
            buckets[(size_t)slice * BUCKET_CAP + pos] = e;
        } else {
            int o = atomicAdd(ovf_cnt, 1);
            if (o < OVF_CAP) ovf[o] = e;
        }
    } else {
        int i = (b - NORM_BLKS) * 256 + threadIdx.x;
        if (i < OUT_F / 4) reinterpret_cast<int4*>(cnt)[i] = make_int4(0, 0, 0, 0);
    }
}

// ===========================================================================
// Kernel B: fused. Blocks [0,CONV_BLKS): x f32 -> bf16 stream (independent).
// Blocks after: bucket -> ELL build; slice = (b2 & 7) keeps each ELL slice
// (0.8 MB) XCD-L2-local under round-robin dispatch (perf heuristic only;
// correctness holds under any mapping since every (chunk,slice) is covered).
// ===========================================================================
__global__ void build_conv_kernel(const float* __restrict__ x,
                                  unsigned* __restrict__ xb,
                                  const int* __restrict__ bcur,
                                  const int2* __restrict__ buckets,
                                  int* __restrict__ cnt,
                                  unsigned* __restrict__ ell,
                                  int* __restrict__ ovf_cnt,
                                  int2* __restrict__ ovf) {
    int b = blockIdx.x;
    if (b < CONV_BLKS) {
        int i = b * 256 + threadIdx.x;
        const float4* x4 = reinterpret_cast<const float4*>(x);
        float4 f0 = x4[2 * i];
        float4 f1 = x4[2 * i + 1];
        uint4 o;
        o.x = pack2_bf16(f0.x, f0.y);
        o.y = pack2_bf16(f0.z, f0.w);
        o.z = pack2_bf16(f1.x, f1.y);
        o.w = pack2_bf16(f1.z, f1.w);
        reinterpret_cast<uint4*>(xb)[i] = o;
        return;
    }
    int b2 = b - CONV_BLKS;
    int slice = b2 & (NXCD - 1);
    int chunk = b2 >> 3;
    int n = bcur[slice];
    if (n > BUCKET_CAP) n = BUCKET_CAP;
    int base = chunk * BUILD_CHUNK + threadIdx.x * 4;
    if (base >= n) return;
    const int2* bk = buckets + (size_t)slice * BUCKET_CAP;
    int4 p01 = *reinterpret_cast<const int4*>(bk + base);
    int4 p23 = *reinterpret_cast<const int4*>(bk + base + 2);
    int2 e[4];
    e[0] = make_int2(p01.x, p01.y); e[1] = make_int2(p01.z, p01.w);
    e[2] = make_int2(p23.x, p23.y); e[3] = make_int2(p23.z, p23.w);
    #pragma unroll
    for (int k = 0; k < 4; ++k) {
        if (base + k < n) {
            int r = e[k].x;
            int pos = atomicAdd(&cnt[r], 1);
            if (pos < ELL_CAP) {
                ell[(size_t)r * ELL_CAP + pos] = (unsigned)e[k].y;
            } else {
                int o = atomicAdd(ovf_cnt, 1);
                if (o < OVF_CAP) ovf[o] = e[k];
            }
        }
    }
}

// ===========================================================================
// SpMM over bf16 x, packed 4B ELL entries (u16 col | bf16 val << 16).
// One wave per row; lane owns 4 batch elems (uint2 = 4 bf16). Unroll-8.
// (Unchanged from round 6: traffic-bound at ~3.8 TB/s L2-miss plateau.)
// ===========================================================================
__global__ void spmm_ell_bf16_kernel(const unsigned short* __restrict__ xb,
                                     const int* __restrict__ cnt_arr,
                                     const unsigned* __restrict__ ell,
                                     const float* __restrict__ bias,
                                     float* __restrict__ out) {
    int r = blockIdx.x * 4 + (threadIdx.x >> 6);
    int lane = threadIdx.x & 63;
    if (r >= OUT_F) return;

    int cnt = cnt_arr[r];
    if (cnt > ELL_CAP) cnt = ELL_CAP;

    unsigned pe = 0;
    if (lane < cnt) pe = ell[(size_t)r * ELL_CAP + lane];

    float bv = bias[r];
    float4 acc = make_float4(bv, bv, bv, bv);
    const uint2* __restrict__ x2 = reinterpret_cast<const uint2*>(xb);

    int j = 0;
    for (; j + 8 <= cnt; j += 8) {
        uint2 g[8]; float v[8];
        #pragma unroll
        for (int k = 0; k < 8; ++k) {
            unsigned e = __shfl(pe, j + k);
            v[k] = __int_as_float((int)(e & 0xFFFF0000u));
            g[k] = x2[(size_t)(e & 0xFFFFu) * 64 + lane];
        }
        #pragma unroll
        for (int k = 0; k < 8; ++k) {
            float a0 = __int_as_float((int)(g[k].x << 16));
            float a1 = __int_as_float((int)(g[k].x & 0xFFFF0000u));
            float a2 = __int_as_float((int)(g[k].y << 16));
            float a3 = __int_as_float((int)(g[k].y & 0xFFFF0000u));
            acc.x += v[k] * a0; acc.y += v[k] * a1;
            acc.z += v[k] * a2; acc.w += v[k] * a3;
        }
    }
    for (; j < cnt; ++j) {
        unsigned e = __shfl(pe, j);
        float vv = __int_as_float((int)(e & 0xFFFF0000u));
        uint2 g = x2[(size_t)(e & 0xFFFFu) * 64 + lane];
        float a0 = __int_as_float((int)(g.x << 16));
        float a1 = __int_as_float((int)(g.x & 0xFFFF0000u));
        float a2 = __int_as_float((int)(g.y << 16));
        float a3 = __int_as_float((int)(g.y & 0xFFFF0000u));
        acc.x += vv * a0; acc.y += vv * a1;
        acc.z += vv * a2; acc.w += vv * a3;
    }
    reinterpret_cast<float4*>(out)[(size_t)r * 64 + lane] = acc;
}

// Apply overflow entries (expected ~0-10): one wave per entry, strided.
__global__ void ovf_apply_kernel(const int* __restrict__ ovf_cnt,
                                 const int2* __restrict__ ovf,
                                 const unsigned short* __restrict__ xb,
                                 float* __restrict__ out) {
    int n = *ovf_cnt;
    if (n > OVF_CAP) n = OVF_CAP;
    int wave = blockIdx.x * 4 + (threadIdx.x >> 6);
    int lane = threadIdx.x & 63;
    const uint2* x2 = reinterpret_cast<const uint2*>(xb);
    for (int e = wave; e < n; e += 256) {
        int2 pk = ovf[e];
        int r = pk.x;
        unsigned cv = (unsigned)pk.y;
        float v = __int_as_float((int)(cv & 0xFFFF0000u));
        uint2 g = x2[(size_t)(cv & 0xFFFFu) * 64 + lane];
        float a0 = __int_as_float((int)(g.x << 16));
        float a1 = __int_as_float((int)(g.x & 0xFFFF0000u));
        float a2 = __int_as_float((int)(g.y << 16));
        float a3 = __int_as_float((int)(g.y & 0xFFFF0000u));
        float* o = out + (size_t)r * BATCH + lane * 4;
        atomicAdd(o + 0, v * a0);
        atomicAdd(o + 1, v * a1);
        atomicAdd(o + 2, v * a2);
        atomicAdd(o + 3, v * a3);
    }
}

// ===========================================================================
// CSR fallback path (round-2, known-good; insurance only)
// ===========================================================================
__global__ void detect_idx_kernel(const unsigned int* __restrict__ idx,
                                  int* __restrict__ flag) {
    if (blockIdx.x == 0 && threadIdx.x == 0) {
        int any_nonzero_hi = 0;
        for (int i = 0; i < 64; ++i)
            if (idx[2 * i + 1] != 0u) any_nonzero_hi = 1;
        *flag = any_nonzero_hi;
    }
}

__global__ void hist_kernel(const void* __restrict__ indices,
                            const int* __restrict__ flag,
                            int* __restrict__ cnt) {
    int i = blockIdx.x * blockDim.x + threadIdx.x;
    if (i >= NNZ_N) return;
    int r = load_index(indices, i, *flag);
    atomicAdd(&cnt[r], 1);
}

#define SCAN_BLOCK 1024
__global__ void scan_kernel(const int* __restrict__ cnt, int* __restrict__ ptr, int n) {
    __shared__ int wsum[16];
    __shared__ int carry;
    int tid = threadIdx.x;
    int lane = tid & 63, wid = tid >> 6;
    if (tid == 0) carry = 0;
    __syncthreads();
    for (int base = 0; base < n; base += SCAN_BLOCK) {
        int i = base + tid;
        int v = (i < n) ? cnt[i] : 0;
        int s = v;
        #pragma unroll
        for (int d = 1; d < 64; d <<= 1) {
            int t = __shfl_up(s, d, 64);
            if (lane >= d) s += t;
        }
        if (lane == 63) wsum[wid] = s;
        __syncthreads();
        if (wid == 0 && lane < 16) {
            int wv = wsum[lane];
            #pragma unroll
            for (int d = 1; d < 16; d <<= 1) {
                int t = __shfl_up(wv, d, 64);
                if (lane >= d) wv += t;
            }
            wsum[lane] = wv;
        }
        __syncthreads();
        int waveoff = (wid == 0) ? 0 : wsum[wid - 1];
        if (i < n) ptr[i] = carry + waveoff + s - v;
        __syncthreads();
        if (tid == SCAN_BLOCK - 1) carry += waveoff + s;
        __syncthreads();
    }
    if (tid == 0) ptr[n] = carry;
}

__global__ void scatter_kernel(const void* __restrict__ indices,
                               const float* __restrict__ values,
                               const int* __restrict__ flag,
                               int* __restrict__ cursor,
                               int* __restrict__ csr_col,
                               float* __restrict__ csr_val) {
    int i = blockIdx.x * blockDim.x + threadIdx.x;
    if (i >= NNZ_N) return;
    int is32 = *flag;
    int r = load_index(indices, i, is32);
    int c = load_index(indices, NNZ_N + i, is32);
    int pos = atomicAdd(&cursor[r], 1);
    csr_col[pos] = c;
    csr_val[pos] = values[i];
}

__global__ void spmm_csr_kernel(const float* __restrict__ x,
                                const int* __restrict__ row_ptr,
                                const int* __restrict__ csr_col,
                                const float* __restrict__ csr_val,
                                const float* __restrict__ bias,
                                float* __restrict__ out) {
    int r = blockIdx.x * 4 + (threadIdx.x >> 6);
    int lane = threadIdx.x & 63;
    if (r >= OUT_F) return;
    float bv = bias[r];
    float4 acc = make_float4(bv, bv, bv, bv);
    int start = row_ptr[r], end = row_ptr[r + 1];
    const float4* x4 = reinterpret_cast<const float4*>(x);
    for (int i = start; i < end; ++i) {
        int c = csr_col[i];
        float v = csr_val[i];
        float4 xv = x4[(size_t)c * 64 + lane];
        acc.x += v * xv.x;
        acc.y += v * xv.y;
        acc.z += v * xv.z;
        acc.w += v * xv.w;
    }
    reinterpret_cast<float4*>(out)[(size_t)r * 64 + lane] = acc;
}

// ===========================================================================
extern "C" void kernel_launch(void* const* d_in, const int* in_sizes, int n_in,
                              void* d_out, int out_size, void* d_ws, size_t ws_size,
                              hipStream_t stream) {
    const float* x       = (const float*)d_in[0];
    const void*  indices = d_in[1];
    const float* values  = (const float*)d_in[2];
    const float* bias    = (const float*)d_in[3];
    float* out = (float*)d_out;
    char* ws = (char*)d_ws;

    if (ws_size >= WS_PART) {
        int*      ovf_cnt = (int*)(ws + OFF_OVFCNT);
        int*      bcur    = (int*)(ws + OFF_BCUR);
        int*      cnt     = (int*)(ws + OFF_ECNT);
        int2*     ovf     = (int2*)(ws + OFF_OVF);
        unsigned* ell     = (unsigned*)(ws + OFF_ELL);
        unsigned* xb      = (unsigned*)(ws + OFF_XB);
        int2*     buckets = (int2*)(ws + OFF_BK);

        // zero ovf_cnt + bucket cursors (cnt[] is zeroed by bin_kernel blocks)
        hipMemsetAsync(ws, 0, 256, stream);

        bin_kernel<<<NORM_BLKS + ZERO_BLKS, 256, 0, stream>>>(
            indices, values, bcur, buckets, cnt, ovf_cnt, ovf);

        build_conv_kernel<<<CONV_BLKS + BUILD_BLKS, 256, 0, stream>>>(
            x, xb, bcur, buckets, cnt, ell, ovf_cnt, ovf);

        spmm_ell_bf16_kernel<<<(OUT_F + 3) / 4, 256, 0, stream>>>(
            (const unsigned short*)xb, cnt, ell, bias, out);

        ovf_apply_kernel<<<64, 256, 0, stream>>>(
            ovf_cnt, ovf, (const unsigned short*)xb, out);
        return;
    }

    // -------- CSR fallback --------
    int* flag = (int*)(ws + OFF_FLAG);
    detect_idx_kernel<<<1, 64, 0, stream>>>((const unsigned int*)indices, flag);

    int*   row_cnt = (int*)(ws + OFF_CNT);
    int*   row_ptr = (int*)(ws + OFF_PTR);
    int*   cursor  = (int*)(ws + OFF_CUR);
    int*   csr_col = (int*)(ws + OFF_COL);
    float* csr_val = (float*)(ws + OFF_VAL);

    hipMemsetAsync(row_cnt, 0, 4 * (OUT_F + 1), stream);
    hist_kernel<<<(NNZ_N + 255) / 256, 256, 0, stream>>>(indices, flag, row_cnt);
    scan_kernel<<<1, SCAN_BLOCK, 0, stream>>>(row_cnt, row_ptr, OUT_F);
    hipMemcpyAsync(cursor, row_ptr, 4 * OUT_F, hipMemcpyDeviceToDevice, stream);
    scatter_kernel<<<(NNZ_N + 255) / 256, 256, 0, stream>>>(indices, values, flag,
                                                            cursor, csr_col, csr_val);
    spmm_csr_kernel<<<(OUT_F + 3) / 4, 256, 0, stream>>>(x, row_ptr, csr_col, csr_val,
                                                         bias, out);
}

// Round 8
// 103.332 us; speedup vs baseline: 1.5344x; 1.5344x over previous
//
#include <hip/hip_runtime.h>
#include <hip/hip_fp16.h>

#define IN_F   50000
#define OUT_F  50000
#define NNZ_N  800000
#define BATCH  256
#define ELL_CAP 32
#define OVF_CAP 4096
#define NXCD    8
#define ROWS_PER_SLICE (OUT_F / NXCD)     // 6250, exact
#define BUILD_CHUNK 1024                  // entries per build block

static constexpr size_t align256(size_t x) { return (x + 255) & ~size_t(255); }

// ---------------- ws layout (int8 ELL path) ----------------
static constexpr size_t OFF_OVFCNT = 0;                                   // int
static constexpr size_t OFF_ECNT   = 256;                                 // OUT_F ints
static constexpr size_t OFF_OVF    = OFF_ECNT + align256(4 * OUT_F);      // OVF_CAP int2
static constexpr size_t OFF_ELL    = OFF_OVF + align256(8 * OVF_CAP);     // OUT_F*ELL_CAP u32
static constexpr size_t OFF_XQ     = OFF_ELL + align256((size_t)4 * OUT_F * ELL_CAP);
static constexpr size_t OFF_SCL    = OFF_XQ + align256((size_t)IN_F * BATCH);
static constexpr size_t OFF_R32    = OFF_SCL + align256(4 * IN_F);
static constexpr size_t OFF_CVP    = OFF_R32 + align256(4 * NNZ_N);
static constexpr size_t WS_PART    = OFF_CVP + align256(4 * NNZ_N);       // ~26 MB

// ---------------- CSR fallback ws layout (insurance only) ----------------
static constexpr size_t OFF_FLAG = 0;
static constexpr size_t OFF_CNT  = 256;
static constexpr size_t OFF_PTR  = OFF_CNT + align256(4 * (OUT_F + 1));
static constexpr size_t OFF_CUR  = OFF_PTR + align256(4 * (OUT_F + 1));
static constexpr size_t OFF_COL  = OFF_CUR + align256(4 * OUT_F);
static constexpr size_t OFF_VAL  = OFF_COL + align256(4 * NNZ_N);
static constexpr size_t WS_CSR   = OFF_VAL + align256(4 * NNZ_N);

// ---------------------------------------------------------------------------
// int64 vs int32 detection: index values < 50000, so int64 hi-words are 0.
// ---------------------------------------------------------------------------
__device__ __forceinline__ int detect_is32_inline(const void* p) {
    const unsigned* u = (const unsigned*)p;
    int is32 = 0;
    #pragma unroll
    for (int k = 0; k < 8; ++k) is32 |= (u[2 * k + 1] != 0u);
    return is32;
}

__device__ __forceinline__ int load_index(const void* p, int elem, int is32) {
    if (is32) return ((const int*)p)[elem];
    return (int)((const long long*)p)[elem];
}

#define QUANT_BLKS (IN_F / 4)                            // 12500 (4 cols/block)
#define ZERO_BLKS  49                                    // ceil(50000/4/256)
#define NORM_BLKS  (NNZ_N / 256)                         // 3125
#define NCHUNK     ((NNZ_N + BUILD_CHUNK - 1) / BUILD_CHUNK)  // 782
#define BUILD_BLKS (NCHUNK * NXCD)                       // 6256

// ===========================================================================
// Kernel 1: per-column int8 quantization of x (wave per column: 256 f32 ->
// max-reduce -> 256 int8 + 1 scale), plus extra blocks that zero cnt[].
// ===========================================================================
__global__ void quant_kernel(const float* __restrict__ x,
                             unsigned* __restrict__ xq,
                             float* __restrict__ scl,
                             int* __restrict__ cnt) {
    int b = blockIdx.x;
    if (b < QUANT_BLKS) {
        int wid = threadIdx.x >> 6, lane = threadIdx.x & 63;
        int c = b * 4 + wid;
        float4 xv = reinterpret_cast<const float4*>(x)[(size_t)c * 64 + lane];
        float m = fmaxf(fmaxf(fabsf(xv.x), fabsf(xv.y)),
                        fmaxf(fabsf(xv.z), fabsf(xv.w)));
        #pragma unroll
        for (int d = 1; d < 64; d <<= 1) m = fmaxf(m, __shfl_xor(m, d, 64));
        float inv = (m > 0.f) ? 127.0f / m : 0.f;
        int q0 = __float2int_rn(xv.x * inv);
        int q1 = __float2int_rn(xv.y * inv);
        int q2 = __float2int_rn(xv.z * inv);
        int q3 = __float2int_rn(xv.w * inv);
        unsigned pk = (unsigned)(q0 & 0xFF) | ((unsigned)(q1 & 0xFF) << 8) |
                      ((unsigned)(q2 & 0xFF) << 16) | ((unsigned)(q3 & 0xFF) << 24);
        xq[(size_t)c * 64 + lane] = pk;
        if (lane == 0) scl[c] = m * (1.0f / 127.0f);
    } else {
        int i = (b - QUANT_BLKS) * 256 + threadIdx.x;
        if (i < OUT_F / 4) reinterpret_cast<int4*>(cnt)[i] = make_int4(0, 0, 0, 0);
    }
}

// ===========================================================================
// Kernel 2: normalize nnz -> r32[] + cvp[] (u16 col | f16(v*scale[col]) << 16).
// scale gather is 4B among a 200 KB hot array (L2-resident).
// ===========================================================================
__global__ void norm_kernel(const void* __restrict__ indices,
                            const float* __restrict__ values,
                            const float* __restrict__ scl,
                            int* __restrict__ r32,
                            unsigned* __restrict__ cvp) {
    int i = blockIdx.x * 256 + threadIdx.x;
    int is32 = detect_is32_inline(indices);
    int r = load_index(indices, i, is32);
    int c = load_index(indices, NNZ_N + i, is32);
    float vs = values[i] * scl[c];
    unsigned short h = __half_as_ushort(__float2half(vs));
    r32[i] = r;
    cvp[i] = (unsigned)(c & 0xFFFF) | ((unsigned)h << 16);
}

// ===========================================================================
// Kernel 3: XCD-partitioned ELL build (round-6 structure, proven). Block b
// scans nnz chunk (b>>3), claims rows in slice (b&7); slice ELL (0.8 MB)
// stays XCD-L2-local under round-robin dispatch (perf heuristic only).
// ===========================================================================
__global__ void build_part_kernel(const int* __restrict__ r32,
                                  const unsigned* __restrict__ cvp,
                                  int* __restrict__ cnt,
                                  unsigned* __restrict__ ell,
                                  int* __restrict__ ovf_cnt,
                                  int2* __restrict__ ovf) {
    int slice = blockIdx.x & (NXCD - 1);
    int chunk = blockIdx.x >> 3;
    int rlo = slice * ROWS_PER_SLICE;
    int rhi = rlo + ROWS_PER_SLICE;
    int base = chunk * BUILD_CHUNK + threadIdx.x * 4;
    if (base >= NNZ_N) return;   // NNZ_N % 4 == 0 -> all 4 entries valid
    int4 rr = *reinterpret_cast<const int4*>(r32 + base);
    #pragma unroll
    for (int k = 0; k < 4; ++k) {
        int r = (&rr.x)[k];
        if (r >= rlo && r < rhi) {
            unsigned e = cvp[base + k];
            int pos = atomicAdd(&cnt[r], 1);
            if (pos < ELL_CAP) {
                ell[(size_t)r * ELL_CAP + pos] = e;
            } else {
                int o = atomicAdd(ovf_cnt, 1);
                if (o < OVF_CAP) ovf[o] = make_int2(r, (int)e);
            }
        }
    }
}

// ===========================================================================
// Kernel 4: SpMM over int8 x. One wave per row; lane owns 4 batch elems
// (1 uint = 4 int8). Gather 256 B/entry (half of bf16). Unroll-8.
// ===========================================================================
__global__ void spmm_ell_i8_kernel(const unsigned* __restrict__ xq,
                                   const int* __restrict__ cnt_arr,
                                   const unsigned* __restrict__ ell,
                                   const float* __restrict__ bias,
                                   float* __restrict__ out) {
    int r = blockIdx.x * 4 + (threadIdx.x >> 6);
    int lane = threadIdx.x & 63;
    if (r >= OUT_F) return;

    int cnt = cnt_arr[r];
    if (cnt > ELL_CAP) cnt = ELL_CAP;

    unsigned pe = 0;
    if (lane < cnt) pe = ell[(size_t)r * ELL_CAP + lane];

    float bv = bias[r];
    float4 acc = make_float4(bv, bv, bv, bv);

    int j = 0;
    for (; j + 8 <= cnt; j += 8) {
        unsigned g[8]; float v[8];
        #pragma unroll
        for (int k = 0; k < 8; ++k) {
            unsigned e = __shfl(pe, j + k);
            v[k] = __half2float(__ushort_as_half((unsigned short)(e >> 16)));
            g[k] = xq[(size_t)(e & 0xFFFFu) * 64 + lane];
        }
        #pragma unroll
        for (int k = 0; k < 8; ++k) {
            acc.x += v[k] * (float)(signed char)(g[k] & 0xFF);
            acc.y += v[k] * (float)(signed char)((g[k] >> 8) & 0xFF);
            acc.z += v[k] * (float)(signed char)((g[k] >> 16) & 0xFF);
            acc.w += v[k] * (float)(signed char)(g[k] >> 24);
        }
    }
    for (; j < cnt; ++j) {
        unsigned e = __shfl(pe, j);
        float vv = __half2float(__ushort_as_half((unsigned short)(e >> 16)));
        unsigned g = xq[(size_t)(e & 0xFFFFu) * 64 + lane];
        acc.x += vv * (float)(signed char)(g & 0xFF);
        acc.y += vv * (float)(signed char)((g >> 8) & 0xFF);
        acc.z += vv * (float)(signed char)((g >> 16) & 0xFF);
        acc.w += vv * (float)(signed char)(g >> 24);
    }
    reinterpret_cast<float4*>(out)[(size_t)r * 64 + lane] = acc;
}

// Apply overflow entries (expected ~0): one wave per entry, strided.
__global__ void ovf_apply_kernel(const int* __restrict__ ovf_cnt,
                                 const int2* __restrict__ ovf,
                                 const unsigned* __restrict__ xq,
                                 float* __restrict__ out) {
    int n = *ovf_cnt;
    if (n > OVF_CAP) n = OVF_CAP;
    int wave = blockIdx.x * 4 + (threadIdx.x >> 6);
    int lane = threadIdx.x & 63;
    for (int e = wave; e < n; e += 256) {
        int2 pk = ovf[e];
        int r = pk.x;
        unsigned cv = (unsigned)pk.y;
        float v = __half2float(__ushort_as_half((unsigned short)(cv >> 16)));
        unsigned g = xq[(size_t)(cv & 0xFFFFu) * 64 + lane];
        float* o = out + (size_t)r * BATCH + lane * 4;
        atomicAdd(o + 0, v * (float)(signed char)(g & 0xFF));
        atomicAdd(o + 1, v * (float)(signed char)((g >> 8) & 0xFF));
        atomicAdd(o + 2, v * (float)(signed char)((g >> 16) & 0xFF));
        atomicAdd(o + 3, v * (float)(signed char)(g >> 24));
    }
}

// ===========================================================================
// CSR fallback path (round-2, known-good; insurance only)
// ===========================================================================
__global__ void detect_idx_kernel(const unsigned int* __restrict__ idx,
                                  int* __restrict__ flag) {
    if (blockIdx.x == 0 && threadIdx.x == 0) {
        int any_nonzero_hi = 0;
        for (int i = 0; i < 64; ++i)
            if (idx[2 * i + 1] != 0u) any_nonzero_hi = 1;
        *flag = any_nonzero_hi;
    }
}

__global__ void hist_kernel(const void* __restrict__ indices,
                            const int* __restrict__ flag,
                            int* __restrict__ cnt) {
    int i = blockIdx.x * blockDim.x + threadIdx.x;
    if (i >= NNZ_N) return;
    int r = load_index(indices, i, *flag);
    atomicAdd(&cnt[r], 1);
}

#define SCAN_BLOCK 1024
__global__ void scan_kernel(const int* __restrict__ cnt, int* __restrict__ ptr, int n) {
    __shared__ int wsum[16];
    __shared__ int carry;
    int tid = threadIdx.x;
    int lane = tid & 63, wid = tid >> 6;
    if (tid == 0) carry = 0;
    __syncthreads();
    for (int base = 0; base < n; base += SCAN_BLOCK) {
        int i = base + tid;
        int v = (i < n) ? cnt[i] : 0;
        int s = v;
        #pragma unroll
        for (int d = 1; d < 64; d <<= 1) {
            int t = __shfl_up(s, d, 64);
            if (lane >= d) s += t;
        }
        if (lane == 63) wsum[wid] = s;
        __syncthreads();
        if (wid == 0 && lane < 16) {
            int wv = wsum[lane];
            #pragma unroll
            for (int d = 1; d < 16; d <<= 1) {
                int t = __shfl_up(wv, d, 64);
                if (lane >= d) wv += t;
            }
            wsum[lane] = wv;
        }
        __syncthreads();
        int waveoff = (wid == 0) ? 0 : wsum[wid - 1];
        if (i < n) ptr[i] = carry + waveoff + s - v;
        __syncthreads();
        if (tid == SCAN_BLOCK - 1) carry += waveoff + s;
        __syncthreads();
    }
    if (tid == 0) ptr[n] = carry;
}

__global__ void scatter_kernel(const void* __restrict__ indices,
                               const float* __restrict__ values,
                               const int* __restrict__ flag,
                               int* __restrict__ cursor,
                               int* __restrict__ csr_col,
                               float* __restrict__ csr_val) {
    int i = blockIdx.x * blockDim.x + threadIdx.x;
    if (i >= NNZ_N) return;
    int is32 = *flag;
    int r = load_index(indices, i, is32);
    int c = load_index(indices, NNZ_N + i, is32);
    int pos = atomicAdd(&cursor[r], 1);
    csr_col[pos] = c;
    csr_val[pos] = values[i];
}

__global__ void spmm_csr_kernel(const float* __restrict__ x,
                                const int* __restrict__ row_ptr,
                                const int* __restrict__ csr_col,
                                const float* __restrict__ csr_val,
                                const float* __restrict__ bias,
                                float* __restrict__ out) {
    int r = blockIdx.x * 4 + (threadIdx.x >> 6);
    int lane = threadIdx.x & 63;
    if (r >= OUT_F) return;
    float bv = bias[r];
    float4 acc = make_float4(bv, bv, bv, bv);
    int start = row_ptr[r], end = row_ptr[r + 1];
    const float4* x4 = reinterpret_cast<const float4*>(x);
    for (int i = start; i < end; ++i) {
        int c = csr_col[i];
        float v = csr_val[i];
        float4 xv = x4[(size_t)c * 64 + lane];
        acc.x += v * xv.x;
        acc.y += v * xv.y;
        acc.z += v * xv.z;
        acc.w += v * xv.w;
    }
    reinterpret_cast<float4*>(out)[(size_t)r * 64 + lane] = acc;
}

// ===========================================================================
extern "C" void kernel_launch(void* const* d_in, const int* in_sizes, int n_in,
                              void* d_out, int out_size, void* d_ws, size_t ws_size,
                              hipStream_t stream) {
    const float* x       = (const float*)d_in[0];
    const void*  indices = d_in[1];
    const float* values  = (const float*)d_in[2];
    const float* bias    = (const float*)d_in[3];
    float* out = (float*)d_out;
    char* ws = (char*)d_ws;

    if (ws_size >= WS_PART) {
        int*      ovf_cnt = (int*)(ws + OFF_OVFCNT);
        int*      cnt     = (int*)(ws + OFF_ECNT);
        int2*     ovf     = (int2*)(ws + OFF_OVF);
        unsigned* ell     = (unsigned*)(ws + OFF_ELL);
        unsigned* xq      = (unsigned*)(ws + OFF_XQ);
        float*    scl     = (float*)(ws + OFF_SCL);
        int*      r32     = (int*)(ws + OFF_R32);
        unsigned* cvp     = (unsigned*)(ws + OFF_CVP);

        // zero ovf_cnt (cnt[] is zeroed by quant_kernel's extra blocks)
        hipMemsetAsync(ws, 0, 256, stream);

        quant_kernel<<<QUANT_BLKS + ZERO_BLKS, 256, 0, stream>>>(x, xq, scl, cnt);

        norm_kernel<<<NORM_BLKS, 256, 0, stream>>>(indices, values, scl, r32, cvp);

        build_part_kernel<<<BUILD_BLKS, 256, 0, stream>>>(r32, cvp, cnt, ell,
                                                          ovf_cnt, ovf);

        spmm_ell_i8_kernel<<<(OUT_F + 3) / 4, 256, 0, stream>>>(
            xq, cnt, ell, bias, out);

        ovf_apply_kernel<<<64, 256, 0, stream>>>(ovf_cnt, ovf, xq, out);
        return;
    }

    // -------- CSR fallback --------
    int* flag = (int*)(ws + OFF_FLAG);
    detect_idx_kernel<<<1, 64, 0, stream>>>((const unsigned int*)indices, flag);

    int*   row_cnt = (int*)(ws + OFF_CNT);
    int*   row_ptr = (int*)(ws + OFF_PTR);
    int*   cursor  = (int*)(ws + OFF_CUR);
    int*   csr_col = (int*)(ws + OFF_COL);
    float* csr_val = (float*)(ws + OFF_VAL);

    hipMemsetAsync(row_cnt, 0, 4 * (OUT_F + 1), stream);
    hist_kernel<<<(NNZ_N + 255) / 256, 256, 0, stream>>>(indices, flag, row_cnt);
    scan_kernel<<<1, SCAN_BLOCK, 0, stream>>>(row_cnt, row_ptr, OUT_F);
    hipMemcpyAsync(cursor, row_ptr, 4 * OUT_F, hipMemcpyDeviceToDevice, stream);
    scatter_kernel<<<(NNZ_N + 255) / 256, 256, 0, stream>>>(indices, values, flag,
                                                            cursor, csr_col, csr_val);
    spmm_csr_kernel<<<(OUT_F + 3) / 4, 256, 0, stream>>>(x, row_ptr, csr_col, csr_val,
                                                         bias, out);
}

// Round 9
// 94.766 us; speedup vs baseline: 1.6731x; 1.0904x over previous
//
#include <hip/hip_runtime.h>
#include <hip/hip_fp16.h>

#define IN_F   50000
#define OUT_F  50000
#define NNZ_N  800000
#define BATCH  256
#define ELL_CAP 32
#define OVF_CAP 4096
#define NXCD    8
#define ROWS_PER_SLICE (OUT_F / NXCD)     // 6250, exact
#define BUILD_CHUNK 1024                  // entries per build block

static constexpr size_t align256(size_t x) { return (x + 255) & ~size_t(255); }

// ---------------- ws layout (int8 ELL path) ----------------
static constexpr size_t OFF_OVFCNT = 0;                                   // int
static constexpr size_t OFF_ECNT   = 256;                                 // OUT_F ints
static constexpr size_t OFF_OVF    = OFF_ECNT + align256(4 * OUT_F);      // OVF_CAP int2
static constexpr size_t OFF_ELL    = OFF_OVF + align256(8 * OVF_CAP);     // OUT_F*ELL_CAP u32
static constexpr size_t OFF_XQ     = OFF_ELL + align256((size_t)4 * OUT_F * ELL_CAP);
static constexpr size_t OFF_SCL    = OFF_XQ + align256((size_t)IN_F * BATCH);
static constexpr size_t OFF_R32    = OFF_SCL + align256(4 * IN_F);
static constexpr size_t OFF_CVP    = OFF_R32 + align256(4 * NNZ_N);
static constexpr size_t WS_PART    = OFF_CVP + align256(4 * NNZ_N);       // ~26 MB

// ---------------- CSR fallback ws layout (insurance only) ----------------
static constexpr size_t OFF_FLAG = 0;
static constexpr size_t OFF_CNT  = 256;
static constexpr size_t OFF_PTR  = OFF_CNT + align256(4 * (OUT_F + 1));
static constexpr size_t OFF_CUR  = OFF_PTR + align256(4 * (OUT_F + 1));
static constexpr size_t OFF_COL  = OFF_CUR + align256(4 * OUT_F);
static constexpr size_t OFF_VAL  = OFF_COL + align256(4 * NNZ_N);
static constexpr size_t WS_CSR   = OFF_VAL + align256(4 * NNZ_N);

// ---------------------------------------------------------------------------
// int64 vs int32 detection: index values < 50000, so int64 hi-words are 0.
// ---------------------------------------------------------------------------
__device__ __forceinline__ int detect_is32_inline(const void* p) {
    const unsigned* u = (const unsigned*)p;
    int is32 = 0;
    #pragma unroll
    for (int k = 0; k < 8; ++k) is32 |= (u[2 * k + 1] != 0u);
    return is32;
}

__device__ __forceinline__ int load_index(const void* p, int elem, int is32) {
    if (is32) return ((const int*)p)[elem];
    return (int)((const long long*)p)[elem];
}

#define NORM_BLKS  (NNZ_N / 256)                         // 3125
#define ZERO_BLKS  49                                    // ceil(50000/4/256)
#define QUANT_BLKS (IN_F / 4)                            // 12500 (4 cols/block)
#define NCHUNK     ((NNZ_N + BUILD_CHUNK - 1) / BUILD_CHUNK)  // 782
#define BUILD_BLKS (NCHUNK * NXCD)                       // 6256

// ===========================================================================
// K1: normalize nnz -> r32[] + cvp[] (u16 col | f16(v*scale[col]) << 16)...
// wait: scale isn't known yet here. Values are packed RAW (f16(v)); the
// scale fold happens in the spmm? No -- see below: we fold scale at K2 time?
// Simplest correct scheme: keep scale fold in cvp, but scale depends on
// quant... so instead we pack f16(v) here and the spmm multiplies by scl[c]?
// That adds a 4B gather per entry in spmm. Better: quantize independent of
// values: scl[c] depends only on x. norm needs scl -> must come after quant.
// Resolution: norm packs RAW f16(v); build copies as-is; spmm computes
// v * scl[c] -- but scl gather in spmm costs a second random 4B load.
// AVOID: fold scl into the int8->float conversion is wrong (per-lane same).
// Actually spmm processes one entry across the whole wave with the SAME c:
// ONE extra scalar-ish load scl[c] per entry, wave-uniform, 200KB L2-hot.
// Cheap (one 4B load per 256B gather, same line reused across waves).
// ===========================================================================
__global__ void norm_zero_kernel(const void* __restrict__ indices,
                                 const float* __restrict__ values,
                                 int* __restrict__ r32,
                                 unsigned* __restrict__ cvp,
                                 int* __restrict__ cnt,
                                 int* __restrict__ ovf_cnt) {
    int b = blockIdx.x;
    if (b < NORM_BLKS) {
        int i = b * 256 + threadIdx.x;
        int is32 = detect_is32_inline(indices);
        int r = load_index(indices, i, is32);
        int c = load_index(indices, NNZ_N + i, is32);
        unsigned short h = __half_as_ushort(__float2half(values[i]));
        r32[i] = r;
        cvp[i] = (unsigned)(c & 0xFFFF) | ((unsigned)h << 16);
    } else {
        int zb = b - NORM_BLKS;
        int i = zb * 256 + threadIdx.x;
        if (i < OUT_F / 4) reinterpret_cast<int4*>(cnt)[i] = make_int4(0, 0, 0, 0);
        if (zb == 0 && threadIdx.x == 0) *ovf_cnt = 0;
    }
}

// ===========================================================================
// K2 fused: blocks [0, BUILD_BLKS): XCD-partitioned ELL build (slice = b&7
// keeps each 0.8 MB ELL slice L2-local under round-robin dispatch; perf
// heuristic only, correctness holds under any mapping). Blocks after:
// per-column int8 quantization of x (wave per column).
// ===========================================================================
__global__ void build_quant_kernel(const int* __restrict__ r32,
                                   const unsigned* __restrict__ cvp,
                                   int* __restrict__ cnt,
                                   unsigned* __restrict__ ell,
                                   int* __restrict__ ovf_cnt,
                                   int2* __restrict__ ovf,
                                   const float* __restrict__ x,
                                   unsigned* __restrict__ xq,
                                   float* __restrict__ scl) {
    int b = blockIdx.x;
    if (b < BUILD_BLKS) {
        int slice = b & (NXCD - 1);
        int chunk = b >> 3;
        int rlo = slice * ROWS_PER_SLICE;
        int rhi = rlo + ROWS_PER_SLICE;
        int base = chunk * BUILD_CHUNK + threadIdx.x * 4;
        if (base >= NNZ_N) return;   // NNZ_N % 4 == 0 -> all 4 entries valid
        int4 rr = *reinterpret_cast<const int4*>(r32 + base);
        #pragma unroll
        for (int k = 0; k < 4; ++k) {
            int r = (&rr.x)[k];
            if (r >= rlo && r < rhi) {
                unsigned e = cvp[base + k];
                int pos = atomicAdd(&cnt[r], 1);
                if (pos < ELL_CAP) {
                    ell[(size_t)r * ELL_CAP + pos] = e;
                } else {
                    int o = atomicAdd(ovf_cnt, 1);
                    if (o < OVF_CAP) ovf[o] = make_int2(r, (int)e);
                }
            }
        }
        return;
    }
    // ---- quant part ----
    int qb = b - BUILD_BLKS;
    int wid = threadIdx.x >> 6, lane = threadIdx.x & 63;
    int c = qb * 4 + wid;
    float4 xv = reinterpret_cast<const float4*>(x)[(size_t)c * 64 + lane];
    float m = fmaxf(fmaxf(fabsf(xv.x), fabsf(xv.y)),
                    fmaxf(fabsf(xv.z), fabsf(xv.w)));
    #pragma unroll
    for (int d = 1; d < 64; d <<= 1) m = fmaxf(m, __shfl_xor(m, d, 64));
    float inv = (m > 0.f) ? 127.0f / m : 0.f;
    int q0 = __float2int_rn(xv.x * inv);
    int q1 = __float2int_rn(xv.y * inv);
    int q2 = __float2int_rn(xv.z * inv);
    int q3 = __float2int_rn(xv.w * inv);
    unsigned pk = (unsigned)(q0 & 0xFF) | ((unsigned)(q1 & 0xFF) << 8) |
                  ((unsigned)(q2 & 0xFF) << 16) | ((unsigned)(q3 & 0xFF) << 24);
    xq[(size_t)c * 64 + lane] = pk;
    if (lane == 0) scl[c] = m * (1.0f / 127.0f);
}

// ===========================================================================
// K3: SpMM over int8 x. One wave per row; lane owns 4 batch elems (1 uint =
// 4 int8). v_eff = f16(v) * scl[c]; scl load is wave-uniform, L2-hot (200KB).
// ===========================================================================
__global__ void spmm_ell_i8_kernel(const unsigned* __restrict__ xq,
                                   const float* __restrict__ scl,
                                   const int* __restrict__ cnt_arr,
                                   const unsigned* __restrict__ ell,
                                   const float* __restrict__ bias,
                                   float* __restrict__ out) {
    int r = blockIdx.x * 4 + (threadIdx.x >> 6);
    int lane = threadIdx.x & 63;
    if (r >= OUT_F) return;

    int cnt = cnt_arr[r];
    if (cnt > ELL_CAP) cnt = ELL_CAP;

    unsigned pe = 0;
    if (lane < cnt) pe = ell[(size_t)r * ELL_CAP + lane];

    float bv = bias[r];
    float4 acc = make_float4(bv, bv, bv, bv);

    int j = 0;
    for (; j + 8 <= cnt; j += 8) {
        unsigned g[8]; float v[8];
        #pragma unroll
        for (int k = 0; k < 8; ++k) {
            unsigned e = __shfl(pe, j + k);
            unsigned c = e & 0xFFFFu;
            v[k] = __half2float(__ushort_as_half((unsigned short)(e >> 16))) * scl[c];
            g[k] = xq[(size_t)c * 64 + lane];
        }
        #pragma unroll
        for (int k = 0; k < 8; ++k) {
            acc.x += v[k] * (float)(signed char)(g[k] & 0xFF);
            acc.y += v[k] * (float)(signed char)((g[k] >> 8) & 0xFF);
            acc.z += v[k] * (float)(signed char)((g[k] >> 16) & 0xFF);
            acc.w += v[k] * (float)(signed char)(g[k] >> 24);
        }
    }
    for (; j < cnt; ++j) {
        unsigned e = __shfl(pe, j);
        unsigned c = e & 0xFFFFu;
        float vv = __half2float(__ushort_as_half((unsigned short)(e >> 16))) * scl[c];
        unsigned g = xq[(size_t)c * 64 + lane];
        acc.x += vv * (float)(signed char)(g & 0xFF);
        acc.y += vv * (float)(signed char)((g >> 8) & 0xFF);
        acc.z += vv * (float)(signed char)((g >> 16) & 0xFF);
        acc.w += vv * (float)(signed char)(g >> 24);
    }
    reinterpret_cast<float4*>(out)[(size_t)r * 64 + lane] = acc;
}

// K4: apply overflow entries (expected ~0): one wave per entry, strided.
__global__ void ovf_apply_kernel(const int* __restrict__ ovf_cnt,
                                 const int2* __restrict__ ovf,
                                 const unsigned* __restrict__ xq,
                                 const float* __restrict__ scl,
                                 float* __restrict__ out) {
    int n = *ovf_cnt;
    if (n > OVF_CAP) n = OVF_CAP;
    int wave = blockIdx.x * 4 + (threadIdx.x >> 6);
    int lane = threadIdx.x & 63;
    for (int e = wave; e < n; e += 256) {
        int2 pk = ovf[e];
        int r = pk.x;
        unsigned cv = (unsigned)pk.y;
        unsigned c = cv & 0xFFFFu;
        float v = __half2float(__ushort_as_half((unsigned short)(cv >> 16))) * scl[c];
        unsigned g = xq[(size_t)c * 64 + lane];
        float* o = out + (size_t)r * BATCH + lane * 4;
        atomicAdd(o + 0, v * (float)(signed char)(g & 0xFF));
        atomicAdd(o + 1, v * (float)(signed char)((g >> 8) & 0xFF));
        atomicAdd(o + 2, v * (float)(signed char)((g >> 16) & 0xFF));
        atomicAdd(o + 3, v * (float)(signed char)(g >> 24));
    }
}

// ===========================================================================
// CSR fallback path (round-2, known-good; insurance only)
// ===========================================================================
__global__ void detect_idx_kernel(const unsigned int* __restrict__ idx,
                                  int* __restrict__ flag) {
    if (blockIdx.x == 0 && threadIdx.x == 0) {
        int any_nonzero_hi = 0;
        for (int i = 0; i < 64; ++i)
            if (idx[2 * i + 1] != 0u) any_nonzero_hi = 1;
        *flag = any_nonzero_hi;
    }
}

__global__ void hist_kernel(const void* __restrict__ indices,
                            const int* __restrict__ flag,
                            int* __restrict__ cnt) {
    int i = blockIdx.x * blockDim.x + threadIdx.x;
    if (i >= NNZ_N) return;
    int r = load_index(indices, i, *flag);
    atomicAdd(&cnt[r], 1);
}

#define SCAN_BLOCK 1024
__global__ void scan_kernel(const int* __restrict__ cnt, int* __restrict__ ptr, int n) {
    __shared__ int wsum[16];
    __shared__ int carry;
    int tid = threadIdx.x;
    int lane = tid & 63, wid = tid >> 6;
    if (tid == 0) carry = 0;
    __syncthreads();
    for (int base = 0; base < n; base += SCAN_BLOCK) {
        int i = base + tid;
        int v = (i < n) ? cnt[i] : 0;
        int s = v;
        #pragma unroll
        for (int d = 1; d < 64; d <<= 1) {
            int t = __shfl_up(s, d, 64);
            if (lane >= d) s += t;
        }
        if (lane == 63) wsum[wid] = s;
        __syncthreads();
        if (wid == 0 && lane < 16) {
            int wv = wsum[lane];
            #pragma unroll
            for (int d = 1; d < 16; d <<= 1) {
                int t = __shfl_up(wv, d, 64);
                if (lane >= d) wv += t;
            }
            wsum[lane] = wv;
        }
        __syncthreads();
        int waveoff = (wid == 0) ? 0 : wsum[wid - 1];
        if (i < n) ptr[i] = carry + waveoff + s - v;
        __syncthreads();
        if (tid == SCAN_BLOCK - 1) carry += waveoff + s;
        __syncthreads();
    }
    if (tid == 0) ptr[n] = carry;
}

__global__ void scatter_kernel(const void* __restrict__ indices,
                               const float* __restrict__ values,
                               const int* __restrict__ flag,
                               int* __restrict__ cursor,
                               int* __restrict__ csr_col,
                               float* __restrict__ csr_val) {
    int i = blockIdx.x * blockDim.x + threadIdx.x;
    if (i >= NNZ_N) return;
    int is32 = *flag;
    int r = load_index(indices, i, is32);
    int c = load_index(indices, NNZ_N + i, is32);
    int pos = atomicAdd(&cursor[r], 1);
    csr_col[pos] = c;
    csr_val[pos] = values[i];
}

__global__ void spmm_csr_kernel(const float* __restrict__ x,
                                const int* __restrict__ row_ptr,
                                const int* __restrict__ csr_col,
                                const float* __restrict__ csr_val,
                                const float* __restrict__ bias,
                                float* __restrict__ out) {
    int r = blockIdx.x * 4 + (threadIdx.x >> 6);
    int lane = threadIdx.x & 63;
    if (r >= OUT_F) return;
    float bv = bias[r];
    float4 acc = make_float4(bv, bv, bv, bv);
    int start = row_ptr[r], end = row_ptr[r + 1];
    const float4* x4 = reinterpret_cast<const float4*>(x);
    for (int i = start; i < end; ++i) {
        int c = csr_col[i];
        float v = csr_val[i];
        float4 xv = x4[(size_t)c * 64 + lane];
        acc.x += v * xv.x;
        acc.y += v * xv.y;
        acc.z += v * xv.z;
        acc.w += v * xv.w;
    }
    reinterpret_cast<float4*>(out)[(size_t)r * 64 + lane] = acc;
}

// ===========================================================================
extern "C" void kernel_launch(void* const* d_in, const int* in_sizes, int n_in,
                              void* d_out, int out_size, void* d_ws, size_t ws_size,
                              hipStream_t stream) {
    const float* x       = (const float*)d_in[0];
    const void*  indices = d_in[1];
    const float* values  = (const float*)d_in[2];
    const float* bias    = (const float*)d_in[3];
    float* out = (float*)d_out;
    char* ws = (char*)d_ws;

    if (ws_size >= WS_PART) {
        int*      ovf_cnt = (int*)(ws + OFF_OVFCNT);
        int*      cnt     = (int*)(ws + OFF_ECNT);
        int2*     ovf     = (int2*)(ws + OFF_OVF);
        unsigned* ell     = (unsigned*)(ws + OFF_ELL);
        unsigned* xq      = (unsigned*)(ws + OFF_XQ);
        float*    scl     = (float*)(ws + OFF_SCL);
        int*      r32     = (int*)(ws + OFF_R32);
        unsigned* cvp     = (unsigned*)(ws + OFF_CVP);

        norm_zero_kernel<<<NORM_BLKS + ZERO_BLKS, 256, 0, stream>>>(
            indices, values, r32, cvp, cnt, ovf_cnt);

        build_quant_kernel<<<BUILD_BLKS + QUANT_BLKS, 256, 0, stream>>>(
            r32, cvp, cnt, ell, ovf_cnt, ovf, x, xq, scl);

        spmm_ell_i8_kernel<<<(OUT_F + 3) / 4, 256, 0, stream>>>(
            xq, scl, cnt, ell, bias, out);

        ovf_apply_kernel<<<64, 256, 0, stream>>>(ovf_cnt, ovf, xq, scl, out);
        return;
    }

    // -------- CSR fallback --------
    int* flag = (int*)(ws + OFF_FLAG);
    detect_idx_kernel<<<1, 64, 0, stream>>>((const unsigned int*)indices, flag);

    int*   row_cnt = (int*)(ws + OFF_CNT);
    int*   row_ptr = (int*)(ws + OFF_PTR);
    int*   cursor  = (int*)(ws + OFF_CUR);
    int*   csr_col = (int*)(ws + OFF_COL);
    float* csr_val = (float*)(ws + OFF_VAL);

    hipMemsetAsync(row_cnt, 0, 4 * (OUT_F + 1), stream);
    hist_kernel<<<(NNZ_N + 255) / 256, 256, 0, stream>>>(indices, flag, row_cnt);
    scan_kernel<<<1, SCAN_BLOCK, 0, stream>>>(row_cnt, row_ptr, OUT_F);
    hipMemcpyAsync(cursor, row_ptr, 4 * OUT_F, hipMemcpyDeviceToDevice, stream);
    scatter_kernel<<<(NNZ_N + 255) / 256, 256, 0, stream>>>(indices, values, flag,
                                                            cursor, csr_col, csr_val);
    spmm_csr_kernel<<<(OUT_F + 3) / 4, 256, 0, stream>>>(x, row_ptr, csr_col, csr_val,
                                                         bias, out);
}